// Round 1
// baseline (1437.423 us; speedup 1.0000x reference)
//
#include <hip/hip_runtime.h>
#include <hip/hip_bf16.h>
#include <stdint.h>

// Problem constants
#define BB 64
#define P0 729
#define CC 1152
#define HD 72        // CC / 16 heads
#define NHEAD 16
#define HH 3584
#define TT 128
#define NSTR 365     // max src count, stride for per-round index arrays

typedef __hip_bfloat16 bf16;
typedef unsigned short u16;
typedef __attribute__((ext_vector_type(8))) short short8;
typedef __attribute__((ext_vector_type(4))) float floatx4;

__device__ inline void load_lds16(const void* g, void* l) {
  __builtin_amdgcn_global_load_lds(
      (const __attribute__((address_space(1))) uint32_t*)g,
      (__attribute__((address_space(3))) uint32_t*)l, 16, 0, 0);
}

// ---------------- init: fp64 head-mean of (x+pos), size=1 ----------------
__global__ void k_init(const float* __restrict__ x, const float* __restrict__ pos,
                       double* __restrict__ mo, int* __restrict__ so) {
  int bp = blockIdx.x;           // b*729+p
  int p = bp % P0;
  const float* xr = x + (size_t)bp * CC;
  const float* pr = pos + (size_t)p * CC;
  int tid = threadIdx.x;         // 128
  if (tid < HD) {
    double s = 0.0;
    #pragma unroll
    for (int h = 0; h < NHEAD; ++h) {
      int c = h * HD + tid;
      s += (double)xr[c] + (double)pr[c];
    }
    mo[(size_t)bp * HD + tid] = s * (1.0 / 16.0);
  }
  if (tid == 0) so[bp] = 1;
}

// ---------------- 1/||m|| per token (fp64) ----------------
__global__ void k_rnorm(const double* __restrict__ m, double* __restrict__ rn, int t) {
  int bi = blockIdx.x;           // b*t + i
  int lane = threadIdx.x;        // 64
  const double* row = m + (size_t)bi * HD;
  double v = 0.0;
  if (lane < HD) { double a = row[lane]; v = a * a; }
  if (lane < HD - 64) { double a = row[lane + 64]; v += a * a; }
  for (int off = 32; off; off >>= 1) v += __shfl_down(v, off, 64);
  if (lane == 0) {
    int b = bi / t, i = bi % t;
    rn[b * P0 + i] = 1.0 / sqrt(v);
  }
}

// ---------------- node_max / node_idx (fp64 cosine scores) ----------------
#define TI 8
#define TJ 32
__global__ __launch_bounds__(256)
void k_score(const double* __restrict__ m, const double* __restrict__ rn,
             double* __restrict__ nmax, int* __restrict__ nidx,
             int t, int s, int d) {
  __shared__ double lsrc[TI][HD + 1];
  __shared__ double ldst[TJ][HD + 1];
  __shared__ double rsrc[TI];
  int b = blockIdx.y;
  int i0 = blockIdx.x * TI;
  int tid = threadIdx.x;
  for (int idx = tid; idx < TI * HD; idx += 256) {
    int il = idx / HD, k = idx % HD;
    int i = i0 + il;
    lsrc[il][k] = (i < s) ? m[((size_t)b * t + 2 * i) * HD + k] : 0.0;
  }
  if (tid < TI) {
    int i = i0 + tid;
    rsrc[tid] = (i < s) ? rn[b * P0 + 2 * i] : 0.0;
  }
  __syncthreads();
  int il = tid >> 5, jl = tid & 31;
  int i = i0 + il;
  double best = -1e300; int bestj = 0x7fffffff;
  for (int c0 = 0; c0 < d; c0 += TJ) {
    for (int idx = tid; idx < TJ * HD; idx += 256) {
      int jj = idx / HD, k = idx % HD;
      int j = c0 + jj;
      ldst[jj][k] = (j < d) ? m[((size_t)b * t + 2 * j + 1) * HD + k] : 0.0;
    }
    __syncthreads();
    int j = c0 + jl;
    if (j < d && i < s) {
      double acc = 0.0;
      #pragma unroll
      for (int k = 0; k < HD; ++k) acc += lsrc[il][k] * ldst[jl][k];
      double sc = acc * rsrc[il] * rn[b * P0 + 2 * j + 1];
      if (sc > best) { best = sc; bestj = j; }   // strict > keeps first max (j ascending)
    }
    __syncthreads();
  }
  for (int off = 16; off; off >>= 1) {
    double ov = __shfl_down(best, off, 32);
    int oj = __shfl_down(bestj, off, 32);
    if (ov > best || (ov == best && oj < bestj)) { best = ov; bestj = oj; }
  }
  if (jl == 0 && i < s) { nmax[b * NSTR + i] = best; nidx[b * NSTR + i] = bestj; }
}

// ---------------- stable descending argsort (bitonic, idx tiebreak) ----------------
__global__ __launch_bounds__(512)
void k_sort(const double* __restrict__ nmax, int* __restrict__ eidx, int s) {
  __shared__ double v[512];
  __shared__ int ix[512];
  int b = blockIdx.x, tid = threadIdx.x;
  if (tid < s) { v[tid] = nmax[b * NSTR + tid]; ix[tid] = tid; }
  else { v[tid] = -1e308; ix[tid] = 1024 + tid; }
  __syncthreads();
  for (int k = 2; k <= 512; k <<= 1)
    for (int j = k >> 1; j > 0; j >>= 1) {
      int l = tid ^ j;
      if (l > tid) {
        double va = v[tid], vb = v[l]; int ia = ix[tid], ib = ix[l];
        bool b_before_a = (vb > va) || (vb == va && ib < ia);
        bool a_before_b = (va > vb) || (va == vb && ia < ib);
        bool dir = ((tid & k) == 0);
        bool sw = dir ? b_before_a : a_before_b;
        if (sw) { v[tid] = vb; v[l] = va; ix[tid] = ib; ix[l] = ia; }
      }
      __syncthreads();
    }
  if (tid < s) eidx[b * NSTR + tid] = ix[tid];
}

// ---------------- size merge (int, exact) ----------------
__global__ __launch_bounds__(512)
void k_size_merge(const int* __restrict__ so, int* __restrict__ sn,
                  const int* __restrict__ eidx, const int* __restrict__ nidx,
                  int r, int unm, int tnew) {
  int b = blockIdx.x, tid = threadIdx.x;
  if (tid < tnew) {
    int tok = (tid < unm) ? 2 * eidx[b * NSTR + r + tid] : 2 * (tid - unm) + 1;
    sn[b * P0 + tid] = so[b * P0 + tok];
  }
  __syncthreads();
  if (tid < r) {
    int si = eidx[b * NSTR + tid];
    int di = nidx[b * NSTR + si];
    atomicAdd(&sn[b * P0 + unm + di], so[b * P0 + 2 * si]);
  }
}

// ---------------- fp64 metric merge: gather then scatter-add ----------------
__global__ void k_gather_d(const double* __restrict__ mo, double* __restrict__ mn,
                           const int* __restrict__ eidx,
                           int t, int r, int unm, int tnew) {
  size_t idx = (size_t)blockIdx.x * 256 + threadIdx.x;
  size_t total = (size_t)BB * tnew * HD;
  if (idx >= total) return;
  int k = idx % HD;
  int o = (idx / HD) % tnew;
  int b = idx / ((size_t)HD * tnew);
  int tok = (o < unm) ? 2 * eidx[b * NSTR + r + o] : 2 * (o - unm) + 1;
  mn[idx] = mo[((size_t)b * t + tok) * HD + k];
}

__global__ void k_scatter_d(const double* __restrict__ mo, double* __restrict__ mn,
                            const int* __restrict__ eidx, const int* __restrict__ nidx,
                            int t, int r, int unm, int tnew) {
  size_t idx = (size_t)blockIdx.x * 256 + threadIdx.x;
  size_t total = (size_t)BB * r * HD;
  if (idx >= total) return;
  int k = idx % HD;
  int q = (idx / HD) % r;
  int b = idx / ((size_t)HD * r);
  int si = eidx[b * NSTR + q];
  int di = nidx[b * NSTR + si];
  atomicAdd(&mn[((size_t)b * tnew + unm + di) * HD + k],
            mo[((size_t)b * t + 2 * si) * HD + k]);
}

// ---------------- fp32 x merge (x kept as running weighted SUM) ----------------
// pos != nullptr only in round 1 (source is the raw input, add pos on the fly)
__global__ void k_gather_f(const float* __restrict__ xo, float* __restrict__ xn,
                           const float* __restrict__ pos,
                           const int* __restrict__ eidx,
                           int t, int r, int unm, int tnew) {
  size_t idx = (size_t)blockIdx.x * 256 + threadIdx.x;   // float4 granularity
  const int C4 = CC / 4;
  size_t total = (size_t)BB * tnew * C4;
  if (idx >= total) return;
  int c4 = idx % C4;
  int o = (idx / C4) % tnew;
  int b = idx / ((size_t)C4 * tnew);
  int tok = (o < unm) ? 2 * eidx[b * NSTR + r + o] : 2 * (o - unm) + 1;
  const float4* src = (const float4*)(xo + ((size_t)b * t + tok) * CC);
  float4 v = src[c4];
  if (pos) {
    const float4* pr = (const float4*)(pos + (size_t)tok * CC);
    float4 pv = pr[c4];
    v.x += pv.x; v.y += pv.y; v.z += pv.z; v.w += pv.w;
  }
  ((float4*)(xn + ((size_t)b * tnew + o) * CC))[c4] = v;
}

__global__ void k_scatter_f(const float* __restrict__ xo, float* __restrict__ xn,
                            const float* __restrict__ pos,
                            const int* __restrict__ eidx, const int* __restrict__ nidx,
                            int t, int r, int unm, int tnew) {
  size_t idx = (size_t)blockIdx.x * 256 + threadIdx.x;
  size_t total = (size_t)BB * r * CC;
  if (idx >= total) return;
  int c = idx % CC;
  int q = (idx / CC) % r;
  int b = idx / ((size_t)CC * r);
  int si = eidx[b * NSTR + q];
  int di = nidx[b * NSTR + si];
  int tok = 2 * si;
  float v = xo[((size_t)b * t + tok) * CC + c];
  if (pos) v += pos[(size_t)tok * CC + c];
  atomicAdd(&xn[((size_t)b * tnew + unm + di) * CC + c], v);
}

// ---------------- divide by size, cast to bf16 ----------------
__global__ void k_finalize(const float* __restrict__ xf, const int* __restrict__ sz,
                           bf16* __restrict__ xb) {
  size_t idx = (size_t)blockIdx.x * 256 + threadIdx.x;
  if (idx >= (size_t)BB * TT * CC) return;
  int o = (idx / CC) % TT;
  int b = idx / ((size_t)CC * TT);
  float v = xf[idx] / (float)sz[b * P0 + o];
  xb[idx] = __float2bfloat16(v);
}

// ---------------- transpose + cast weights: (K,N) fp32 -> (N,K) bf16 ----------------
__global__ void k_transpose(const float* __restrict__ w, bf16* __restrict__ wt,
                            int K, int N) {
  __shared__ float tile[32][33];
  int n0 = blockIdx.x * 32, k0 = blockIdx.y * 32;
  int tx = threadIdx.x, ty = threadIdx.y;   // 32 x 8
  #pragma unroll
  for (int yy = 0; yy < 32; yy += 8)
    tile[ty + yy][tx] = w[(size_t)(k0 + ty + yy) * N + n0 + tx];
  __syncthreads();
  #pragma unroll
  for (int yy = 0; yy < 32; yy += 8)
    wt[(size_t)(n0 + ty + yy) * K + k0 + tx] = __float2bfloat16(tile[tx][ty + yy]);
}

// ---------------- bf16 MFMA GEMM, A (M,K) row-major, Bt (N,K) row-major ----------------
// EPI 0: out = bf16(gelu_exact(acc + bias))   EPI 1: out = fp32(acc + bias)
template <int EPI>
__global__ __launch_bounds__(256)
void k_gemm(const u16* __restrict__ A, const u16* __restrict__ Bt,
            const float* __restrict__ bias, void* __restrict__ Cout,
            int M, int N, int K) {
  __shared__ u16 sA[128 * 32];
  __shared__ u16 sB[128 * 32];
  int tid = threadIdx.x;
  int m0 = blockIdx.y * 128, n0 = blockIdx.x * 128;
  int wave = tid >> 6, lane = tid & 63;
  int wm = (wave & 1) * 64, wn = (wave >> 1) * 64;
  int quad = lane >> 4, lrow = lane & 15;
  floatx4 acc[4][4] = {};
  const u16* gA = A + (size_t)(m0 + tid / 4) * K + (tid % 4) * 8;
  const u16* gB = Bt + (size_t)(n0 + tid / 4) * K + (tid % 4) * 8;
  for (int k0 = 0; k0 < K; k0 += 32) {
    load_lds16(gA + k0, &sA[tid * 8]);
    load_lds16(gA + (size_t)64 * K + k0, &sA[2048 + tid * 8]);
    load_lds16(gB + k0, &sB[tid * 8]);
    load_lds16(gB + (size_t)64 * K + k0, &sB[2048 + tid * 8]);
    __syncthreads();
    short8 af[4], bfr[4];
    #pragma unroll
    for (int mt = 0; mt < 4; ++mt)
      af[mt] = *(const short8*)&sA[(wm + mt * 16 + lrow) * 32 + quad * 8];
    #pragma unroll
    for (int nt = 0; nt < 4; ++nt)
      bfr[nt] = *(const short8*)&sB[(wn + nt * 16 + lrow) * 32 + quad * 8];
    #pragma unroll
    for (int mt = 0; mt < 4; ++mt)
      #pragma unroll
      for (int nt = 0; nt < 4; ++nt)
        acc[mt][nt] = __builtin_amdgcn_mfma_f32_16x16x32_bf16(af[mt], bfr[nt], acc[mt][nt], 0, 0, 0);
    __syncthreads();
  }
  #pragma unroll
  for (int mt = 0; mt < 4; ++mt)
    #pragma unroll
    for (int nt = 0; nt < 4; ++nt)
      #pragma unroll
      for (int rg = 0; rg < 4; ++rg) {
        int row = m0 + wm + mt * 16 + quad * 4 + rg;
        int col = n0 + wn + nt * 16 + lrow;
        float v = acc[mt][nt][rg] + bias[col];
        if (EPI == 0) {
          float g = 0.5f * v * (1.0f + erff(v * 0.70710678118654752f));
          ((bf16*)Cout)[(size_t)row * N + col] = __float2bfloat16(g);
        } else {
          ((float*)Cout)[(size_t)row * N + col] = v;
        }
      }
}

extern "C" void kernel_launch(void* const* d_in, const int* in_sizes, int n_in,
                              void* d_out, int out_size, void* d_ws, size_t ws_size,
                              hipStream_t stream) {
  const float* x   = (const float*)d_in[0];
  const float* pos = (const float*)d_in[1];
  const float* w1  = (const float*)d_in[2];
  const float* b1  = (const float*)d_in[3];
  const float* w2  = (const float*)d_in[4];
  const float* b2  = (const float*)d_in[5];

  uint8_t* wsp = (uint8_t*)d_ws;
  size_t off = 0;
  auto alloc = [&](size_t bytes) -> void* {
    void* p = wsp + off;
    off += (bytes + 255) & ~(size_t)255;
    return p;
  };
  double* m_a  = (double*)alloc((size_t)BB * P0 * HD * 8);      // 26.9 MB
  double* m_b  = (double*)alloc((size_t)BB * NSTR * HD * 8);    // 13.5 MB
  float*  x_b  = (float*)alloc((size_t)BB * NSTR * CC * 4);     // 107.6 MB (round1 out)
  float*  x_c  = (float*)alloc((size_t)BB * 183 * CC * 4);      // 54 MB (round2 out)
  int*    s_a  = (int*)alloc((size_t)BB * P0 * 4);
  int*    s_b  = (int*)alloc((size_t)BB * P0 * 4);
  double* rn   = (double*)alloc((size_t)BB * P0 * 8);
  double* nmax = (double*)alloc((size_t)BB * NSTR * 8);
  int*    nidx = (int*)alloc((size_t)BB * NSTR * 4);
  int*    eidx = (int*)alloc((size_t)BB * NSTR * 4);
  bf16*   xb   = (bf16*)alloc((size_t)BB * TT * CC * 2);        // 18.9 MB
  bf16*   w1t  = (bf16*)alloc((size_t)HH * CC * 2);             // 8.3 MB
  bf16*   w2t  = (bf16*)alloc((size_t)HH * HH * 2);             // 25.7 MB
  bf16*   hb   = (bf16*)alloc((size_t)BB * TT * HH * 2);        // 58.7 MB

  k_init<<<BB * P0, 128, 0, stream>>>(x, pos, m_a, s_a);
  dim3 tb(32, 8);
  k_transpose<<<dim3(HH / 32, CC / 32), tb, 0, stream>>>(w1, w1t, CC, HH);
  k_transpose<<<dim3(HH / 32, HH / 32), tb, 0, stream>>>(w2, w2t, HH, HH);

  struct Rnd { int t, s, d, r, unm, tnew; };
  const Rnd R[3] = {{729, 365, 364, 364, 1, 365},
                    {365, 183, 182, 182, 1, 183},
                    {183,  92,  91,  55, 37, 128}};
  const float* xsrc[3] = {x, x_b, x_c};
  float*       xdst[3] = {x_b, x_c, x_b};
  const float* posr[3] = {pos, nullptr, nullptr};
  double*      msrc[3] = {m_a, m_b, m_a};
  double*      mdst[3] = {m_b, m_a, m_b};
  int*         ssrc[3] = {s_a, s_b, s_a};
  int*         sdst[3] = {s_b, s_a, s_b};

  for (int rr = 0; rr < 3; ++rr) {
    Rnd q = R[rr];
    k_rnorm<<<BB * q.t, 64, 0, stream>>>(msrc[rr], rn, q.t);
    dim3 sg((q.s + TI - 1) / TI, BB);
    k_score<<<sg, 256, 0, stream>>>(msrc[rr], rn, nmax, nidx, q.t, q.s, q.d);
    k_sort<<<BB, 512, 0, stream>>>(nmax, eidx, q.s);
    k_size_merge<<<BB, 512, 0, stream>>>(ssrc[rr], sdst[rr], eidx, nidx, q.r, q.unm, q.tnew);
    size_t tg = (size_t)BB * q.tnew * HD;
    k_gather_d<<<(tg + 255) / 256, 256, 0, stream>>>(msrc[rr], mdst[rr], eidx, q.t, q.r, q.unm, q.tnew);
    size_t ts = (size_t)BB * q.r * HD;
    k_scatter_d<<<(ts + 255) / 256, 256, 0, stream>>>(msrc[rr], mdst[rr], eidx, nidx, q.t, q.r, q.unm, q.tnew);
    size_t tgf = (size_t)BB * q.tnew * (CC / 4);
    k_gather_f<<<(tgf + 255) / 256, 256, 0, stream>>>(xsrc[rr], xdst[rr], posr[rr], eidx, q.t, q.r, q.unm, q.tnew);
    size_t tsf = (size_t)BB * q.r * CC;
    k_scatter_f<<<(tsf + 255) / 256, 256, 0, stream>>>(xsrc[rr], xdst[rr], posr[rr], eidx, nidx, q.t, q.r, q.unm, q.tnew);
  }

  // final tokens: x_b (128/token), sizes: s_b
  size_t fin = (size_t)BB * TT * CC;
  k_finalize<<<(fin + 255) / 256, 256, 0, stream>>>(x_b, s_b, xb);

  // GEMM1: (8192 x 1152) x (1152 x 3584) -> gelu -> hb (bf16)
  k_gemm<0><<<dim3(HH / 128, (BB * TT) / 128), 256, 0, stream>>>(
      (const u16*)xb, (const u16*)w1t, b1, hb, BB * TT, HH, CC);
  // GEMM2: (8192 x 3584) x (3584 x 3584) -> + b2 -> d_out (fp32)
  k_gemm<1><<<dim3(HH / 128, (BB * TT) / 128), 256, 0, stream>>>(
      (const u16*)hb, (const u16*)w2t, b2, d_out, BB * TT, HH, HH);
}

// Round 3
// 1431.547 us; speedup vs baseline: 1.0041x; 1.0041x over previous
//
#include <hip/hip_runtime.h>
#include <hip/hip_bf16.h>
#include <stdint.h>

// Problem constants
#define BB 64
#define P0 729
#define CC 1152
#define HD 72        // CC / 16 heads
#define NHEAD 16
#define HH 3584
#define TT 128
#define NSTR 365     // max src count, stride for per-round index arrays

typedef __hip_bfloat16 bf16;
typedef unsigned short u16;
typedef __attribute__((ext_vector_type(8))) short short8;
typedef __attribute__((ext_vector_type(4))) float floatx4;

__device__ inline u16 f2bf(float v) {
  bf16 h = __float2bfloat16(v);
  return *(u16*)&h;
}

__device__ inline void load_lds16(const void* g, void* l) {
  __builtin_amdgcn_global_load_lds(
      (const __attribute__((address_space(1))) uint32_t*)g,
      (__attribute__((address_space(3))) uint32_t*)l, 16, 0, 0);
}

// ---------------- init: fp64 head-mean of (x+pos), amap = identity ----------------
__global__ void k_init(const float* __restrict__ x, const float* __restrict__ pos,
                       double* __restrict__ mo, int* __restrict__ amap) {
  int bp = blockIdx.x;           // b*729+p
  int p = bp % P0;
  const float* xr = x + (size_t)bp * CC;
  const float* pr = pos + (size_t)p * CC;
  int tid = threadIdx.x;         // 128
  if (tid < HD) {
    double s = 0.0;
    #pragma unroll
    for (int h = 0; h < NHEAD; ++h) {
      int c = h * HD + tid;
      s += (double)xr[c] + (double)pr[c];
    }
    mo[(size_t)bp * HD + tid] = s * (1.0 / 16.0);
  }
  if (tid == 0) amap[bp] = p;
}

// ---------------- 1/||m|| per token (fp64) ----------------
__global__ void k_rnorm(const double* __restrict__ m, double* __restrict__ rn, int t) {
  int bi = blockIdx.x;           // b*t + i
  int lane = threadIdx.x;        // 64
  const double* row = m + (size_t)bi * HD;
  double v = 0.0;
  if (lane < HD) { double a = row[lane]; v = a * a; }
  if (lane < HD - 64) { double a = row[lane + 64]; v += a * a; }
  for (int off = 32; off; off >>= 1) v += __shfl_down(v, off, 64);
  if (lane == 0) {
    int b = bi / t, i = bi % t;
    rn[b * P0 + i] = 1.0 / sqrt(v);
  }
}

// ---------------- node_max / node_idx (fp64 cosine scores) ----------------
#define TI 8
#define TJ 32
__global__ __launch_bounds__(256)
void k_score(const double* __restrict__ m, const double* __restrict__ rn,
             double* __restrict__ nmax, int* __restrict__ nidx,
             int t, int s, int d) {
  __shared__ double lsrc[TI][HD + 1];
  __shared__ double ldst[TJ][HD + 1];
  __shared__ double rsrc[TI];
  int b = blockIdx.y;
  int i0 = blockIdx.x * TI;
  int tid = threadIdx.x;
  for (int idx = tid; idx < TI * HD; idx += 256) {
    int il = idx / HD, k = idx % HD;
    int i = i0 + il;
    lsrc[il][k] = (i < s) ? m[((size_t)b * t + 2 * i) * HD + k] : 0.0;
  }
  if (tid < TI) {
    int i = i0 + tid;
    rsrc[tid] = (i < s) ? rn[b * P0 + 2 * i] : 0.0;
  }
  __syncthreads();
  int il = tid >> 5, jl = tid & 31;
  int i = i0 + il;
  double best = -1e300; int bestj = 0x7fffffff;
  for (int c0 = 0; c0 < d; c0 += TJ) {
    for (int idx = tid; idx < TJ * HD; idx += 256) {
      int jj = idx / HD, k = idx % HD;
      int j = c0 + jj;
      ldst[jj][k] = (j < d) ? m[((size_t)b * t + 2 * j + 1) * HD + k] : 0.0;
    }
    __syncthreads();
    int j = c0 + jl;
    if (j < d && i < s) {
      double acc = 0.0;
      #pragma unroll
      for (int k = 0; k < HD; ++k) acc += lsrc[il][k] * ldst[jl][k];
      double sc = acc * rsrc[il] * rn[b * P0 + 2 * j + 1];
      if (sc > best) { best = sc; bestj = j; }   // strict > keeps first max (j ascending)
    }
    __syncthreads();
  }
  for (int off = 16; off; off >>= 1) {
    double ov = __shfl_down(best, off, 32);
    int oj = __shfl_down(bestj, off, 32);
    if (ov > best || (ov == best && oj < bestj)) { best = ov; bestj = oj; }
  }
  if (jl == 0 && i < s) { nmax[b * NSTR + i] = best; nidx[b * NSTR + i] = bestj; }
}

// ---------------- stable descending argsort (bitonic, idx tiebreak) ----------------
template <int SZ>
__global__ __launch_bounds__(512)
void k_sort(const double* __restrict__ nmax, int* __restrict__ eidx, int s) {
  __shared__ double v[SZ];
  __shared__ int ix[SZ];
  int b = blockIdx.x, tid = threadIdx.x;
  if (tid < s) { v[tid] = nmax[b * NSTR + tid]; ix[tid] = tid; }
  else { v[tid] = -1e308; ix[tid] = 1024 + tid; }
  __syncthreads();
  for (int k = 2; k <= SZ; k <<= 1)
    for (int j = k >> 1; j > 0; j >>= 1) {
      int l = tid ^ j;
      if (l > tid) {
        double va = v[tid], vb = v[l]; int ia = ix[tid], ib = ix[l];
        bool b_before_a = (vb > va) || (vb == va && ib < ia);
        bool a_before_b = (va > vb) || (va == vb && ia < ib);
        bool dir = ((tid & k) == 0);
        bool sw = dir ? b_before_a : a_before_b;
        if (sw) { v[tid] = vb; v[l] = va; ix[tid] = ib; ix[l] = ia; }
      }
      __syncthreads();
    }
  if (tid < s) eidx[b * NSTR + tid] = ix[tid];
}

// ---------------- compose per-round old->new map into amap (orig token -> slot) ----
__global__ __launch_bounds__(512)
void k_mapround(const int* __restrict__ eidx, const int* __restrict__ nidx,
                int* __restrict__ amap, int t, int s, int r, int unm) {
  __shared__ int pos_of[NSTR];
  __shared__ int rmap[P0];
  int b = blockIdx.x, tid = threadIdx.x;
  for (int q = tid; q < s; q += 512) pos_of[eidx[b * NSTR + q]] = q;
  __syncthreads();
  for (int j = tid; j < t; j += 512) {
    int nm;
    if (j & 1) {
      nm = unm + (j >> 1);                      // odd token = dst jd -> unm + jd
    } else {
      int i = j >> 1;                           // even token = src i
      int q = pos_of[i];
      nm = (q >= r) ? (q - r)                   // unmerged: position in unm block
                    : (unm + nidx[b * NSTR + i]); // merged into its dst
    }
    rmap[j] = nm;
  }
  __syncthreads();
  for (int p = tid; p < P0; p += 512) {
    int cur = amap[b * P0 + p];
    amap[b * P0 + p] = rmap[cur];
  }
}

// ---------------- fp64 metric merge: gather then scatter-add ----------------
__global__ void k_gather_d(const double* __restrict__ mo, double* __restrict__ mn,
                           const int* __restrict__ eidx,
                           int t, int r, int unm, int tnew) {
  size_t idx = (size_t)blockIdx.x * 256 + threadIdx.x;
  size_t total = (size_t)BB * tnew * HD;
  if (idx >= total) return;
  int k = idx % HD;
  int o = (idx / HD) % tnew;
  int b = idx / ((size_t)HD * tnew);
  int tok = (o < unm) ? 2 * eidx[b * NSTR + r + o] : 2 * (o - unm) + 1;
  mn[idx] = mo[((size_t)b * t + tok) * HD + k];
}

__global__ void k_scatter_d(const double* __restrict__ mo, double* __restrict__ mn,
                            const int* __restrict__ eidx, const int* __restrict__ nidx,
                            int t, int r, int unm, int tnew) {
  size_t idx = (size_t)blockIdx.x * 256 + threadIdx.x;
  size_t total = (size_t)BB * r * HD;
  if (idx >= total) return;
  int k = idx % HD;
  int q = (idx / HD) % r;
  int b = idx / ((size_t)HD * r);
  int si = eidx[b * NSTR + q];
  int di = nidx[b * NSTR + si];
  atomicAdd(&mn[((size_t)b * tnew + unm + di) * HD + k],
            mo[((size_t)b * t + 2 * si) * HD + k]);
}

// ---------------- CSR build: counts (=sizes), offsets, member lists ----------------
__global__ __launch_bounds__(256)
void k_buildcsr(const int* __restrict__ amap, int* __restrict__ sizes,
                int* __restrict__ offs, int* __restrict__ list) {
  __shared__ int cnt[TT], off_s[TT], cur[TT];
  int b = blockIdx.x, tid = threadIdx.x;
  if (tid < TT) { cnt[tid] = 0; cur[tid] = 0; }
  __syncthreads();
  for (int p = tid; p < P0; p += 256) atomicAdd(&cnt[amap[b * P0 + p]], 1);
  __syncthreads();
  if (tid == 0) {
    int acc = 0;
    for (int o = 0; o < TT; ++o) { off_s[o] = acc; acc += cnt[o]; }
  }
  __syncthreads();
  if (tid < TT) { sizes[b * TT + tid] = cnt[tid]; offs[b * TT + tid] = off_s[tid]; }
  for (int p = tid; p < P0; p += 256) {
    int o = amap[b * P0 + p];
    int pos = atomicAdd(&cur[o], 1);
    list[b * P0 + off_s[o] + pos] = p;
  }
}

// ---------------- final assembly: sum assigned (x+pos) rows, /size, -> bf16 --------
__global__ __launch_bounds__(256)
void k_assemble(const float* __restrict__ x, const float* __restrict__ pos,
                const int* __restrict__ sizes, const int* __restrict__ offs,
                const int* __restrict__ list, bf16* __restrict__ xb) {
  int o = blockIdx.x, b = blockIdx.y, tid = threadIdx.x;
  int n = sizes[b * TT + o];
  int off = offs[b * TT + o];
  const int C4 = CC / 4;  // 288 float4 per row; thread covers tid and tid+256 (if <32)
  float4 a0 = {0.f, 0.f, 0.f, 0.f}, a1 = {0.f, 0.f, 0.f, 0.f};
  for (int i = 0; i < n; ++i) {
    int p = list[b * P0 + off + i];
    const float4* xr = (const float4*)(x + ((size_t)b * P0 + p) * CC);
    const float4* pr = (const float4*)(pos + (size_t)p * CC);
    float4 v = xr[tid], w = pr[tid];
    a0.x += v.x + w.x; a0.y += v.y + w.y; a0.z += v.z + w.z; a0.w += v.w + w.w;
    if (tid < C4 - 256) {
      float4 v1 = xr[tid + 256], w1 = pr[tid + 256];
      a1.x += v1.x + w1.x; a1.y += v1.y + w1.y; a1.z += v1.z + w1.z; a1.w += v1.w + w1.w;
    }
  }
  float inv = 1.0f / (float)n;
  bf16* orow = xb + ((size_t)b * TT + o) * CC;
  ushort4 pk;
  pk.x = f2bf(a0.x * inv);
  pk.y = f2bf(a0.y * inv);
  pk.z = f2bf(a0.z * inv);
  pk.w = f2bf(a0.w * inv);
  ((ushort4*)orow)[tid] = pk;
  if (tid < C4 - 256) {
    ushort4 pk1;
    pk1.x = f2bf(a1.x * inv);
    pk1.y = f2bf(a1.y * inv);
    pk1.z = f2bf(a1.z * inv);
    pk1.w = f2bf(a1.w * inv);
    ((ushort4*)orow)[tid + 256] = pk1;
  }
}

// ---------------- transpose + cast weights: (K,N) fp32 -> (N,K) bf16 ----------------
__global__ void k_transpose(const float* __restrict__ w, bf16* __restrict__ wt,
                            int K, int N) {
  __shared__ float tile[32][33];
  int n0 = blockIdx.x * 32, k0 = blockIdx.y * 32;
  int tx = threadIdx.x, ty = threadIdx.y;   // 32 x 8
  #pragma unroll
  for (int yy = 0; yy < 32; yy += 8)
    tile[ty + yy][tx] = w[(size_t)(k0 + ty + yy) * N + n0 + tx];
  __syncthreads();
  #pragma unroll
  for (int yy = 0; yy < 32; yy += 8)
    wt[(size_t)(n0 + ty + yy) * K + k0 + tx] = __float2bfloat16(tile[tx][ty + yy]);
}

// ---------------- bf16 MFMA GEMM, A (M,K) row-major, Bt (N,K) row-major ----------------
// EPI 0: out = bf16(gelu_exact(acc + bias))   EPI 1: out = fp32(acc + bias)
template <int EPI>
__global__ __launch_bounds__(256)
void k_gemm(const u16* __restrict__ A, const u16* __restrict__ Bt,
            const float* __restrict__ bias, void* __restrict__ Cout,
            int M, int N, int K) {
  __shared__ u16 sA[128 * 32];
  __shared__ u16 sB[128 * 32];
  int tid = threadIdx.x;
  int m0 = blockIdx.y * 128, n0 = blockIdx.x * 128;
  int wave = tid >> 6, lane = tid & 63;
  int wm = (wave & 1) * 64, wn = (wave >> 1) * 64;
  int quad = lane >> 4, lrow = lane & 15;
  floatx4 acc[4][4] = {};
  const u16* gA = A + (size_t)(m0 + tid / 4) * K + (tid % 4) * 8;
  const u16* gB = Bt + (size_t)(n0 + tid / 4) * K + (tid % 4) * 8;
  for (int k0 = 0; k0 < K; k0 += 32) {
    load_lds16(gA + k0, &sA[tid * 8]);
    load_lds16(gA + (size_t)64 * K + k0, &sA[2048 + tid * 8]);
    load_lds16(gB + k0, &sB[tid * 8]);
    load_lds16(gB + (size_t)64 * K + k0, &sB[2048 + tid * 8]);
    __syncthreads();
    short8 af[4], bfr[4];
    #pragma unroll
    for (int mt = 0; mt < 4; ++mt)
      af[mt] = *(const short8*)&sA[(wm + mt * 16 + lrow) * 32 + quad * 8];
    #pragma unroll
    for (int nt = 0; nt < 4; ++nt)
      bfr[nt] = *(const short8*)&sB[(wn + nt * 16 + lrow) * 32 + quad * 8];
    #pragma unroll
    for (int mt = 0; mt < 4; ++mt)
      #pragma unroll
      for (int nt = 0; nt < 4; ++nt)
        acc[mt][nt] = __builtin_amdgcn_mfma_f32_16x16x32_bf16(af[mt], bfr[nt], acc[mt][nt], 0, 0, 0);
    __syncthreads();
  }
  #pragma unroll
  for (int mt = 0; mt < 4; ++mt)
    #pragma unroll
    for (int nt = 0; nt < 4; ++nt)
      #pragma unroll
      for (int rg = 0; rg < 4; ++rg) {
        int row = m0 + wm + mt * 16 + quad * 4 + rg;
        int col = n0 + wn + nt * 16 + lrow;
        float v = acc[mt][nt][rg] + bias[col];
        if (EPI == 0) {
          float g = 0.5f * v * (1.0f + erff(v * 0.70710678118654752f));
          ((bf16*)Cout)[(size_t)row * N + col] = __float2bfloat16(g);
        } else {
          ((float*)Cout)[(size_t)row * N + col] = v;
        }
      }
}

extern "C" void kernel_launch(void* const* d_in, const int* in_sizes, int n_in,
                              void* d_out, int out_size, void* d_ws, size_t ws_size,
                              hipStream_t stream) {
  const float* x   = (const float*)d_in[0];
  const float* pos = (const float*)d_in[1];
  const float* w1  = (const float*)d_in[2];
  const float* b1  = (const float*)d_in[3];
  const float* w2  = (const float*)d_in[4];
  const float* b2  = (const float*)d_in[5];

  uint8_t* wsp = (uint8_t*)d_ws;
  size_t off = 0;
  auto alloc = [&](size_t bytes) -> void* {
    void* p = wsp + off;
    off += (bytes + 255) & ~(size_t)255;
    return p;
  };
  double* m_a  = (double*)alloc((size_t)BB * P0 * HD * 8);      // 26.9 MB
  double* m_b  = (double*)alloc((size_t)BB * NSTR * HD * 8);    // 13.5 MB
  double* rn   = (double*)alloc((size_t)BB * P0 * 8);
  double* nmax = (double*)alloc((size_t)BB * NSTR * 8);
  int*    nidx = (int*)alloc((size_t)BB * NSTR * 4);
  int*    eidx = (int*)alloc((size_t)BB * NSTR * 4);
  int*    amap = (int*)alloc((size_t)BB * P0 * 4);
  int*    szs  = (int*)alloc((size_t)BB * TT * 4);
  int*    offs = (int*)alloc((size_t)BB * TT * 4);
  int*    list = (int*)alloc((size_t)BB * P0 * 4);
  bf16*   xb   = (bf16*)alloc((size_t)BB * TT * CC * 2);        // 18.9 MB
  bf16*   w1t  = (bf16*)alloc((size_t)HH * CC * 2);             // 8.3 MB
  bf16*   w2t  = (bf16*)alloc((size_t)HH * HH * 2);             // 25.7 MB
  bf16*   hb   = (bf16*)alloc((size_t)BB * TT * HH * 2);        // 58.7 MB

  k_init<<<BB * P0, 128, 0, stream>>>(x, pos, m_a, amap);
  dim3 tb(32, 8);
  k_transpose<<<dim3(HH / 32, CC / 32), tb, 0, stream>>>(w1, w1t, CC, HH);
  k_transpose<<<dim3(HH / 32, HH / 32), tb, 0, stream>>>(w2, w2t, HH, HH);

  struct Rnd { int t, s, d, r, unm, tnew; };
  const Rnd R[3] = {{729, 365, 364, 364, 1, 365},
                    {365, 183, 182, 182, 1, 183},
                    {183,  92,  91,  55, 37, 128}};
  double* msrc[3] = {m_a, m_b, m_a};
  double* mdst[3] = {m_b, m_a, m_b};

  for (int rr = 0; rr < 3; ++rr) {
    Rnd q = R[rr];
    k_rnorm<<<BB * q.t, 64, 0, stream>>>(msrc[rr], rn, q.t);
    dim3 sg((q.s + TI - 1) / TI, BB);
    k_score<<<sg, 256, 0, stream>>>(msrc[rr], rn, nmax, nidx, q.t, q.s, q.d);
    if (rr == 0)      k_sort<512><<<BB, 512, 0, stream>>>(nmax, eidx, q.s);
    else if (rr == 1) k_sort<256><<<BB, 256, 0, stream>>>(nmax, eidx, q.s);
    else              k_sort<128><<<BB, 128, 0, stream>>>(nmax, eidx, q.s);
    k_mapround<<<BB, 512, 0, stream>>>(eidx, nidx, amap, q.t, q.s, q.r, q.unm);
    if (rr < 2) {  // metric for next round only
      size_t tg = (size_t)BB * q.tnew * HD;
      k_gather_d<<<(tg + 255) / 256, 256, 0, stream>>>(msrc[rr], mdst[rr], eidx, q.t, q.r, q.unm, q.tnew);
      size_t ts = (size_t)BB * q.r * HD;
      k_scatter_d<<<(ts + 255) / 256, 256, 0, stream>>>(msrc[rr], mdst[rr], eidx, nidx, q.t, q.r, q.unm, q.tnew);
    }
  }

  k_buildcsr<<<BB, 256, 0, stream>>>(amap, szs, offs, list);
  k_assemble<<<dim3(TT, BB), 256, 0, stream>>>(x, pos, szs, offs, list, xb);

  // GEMM1: (8192 x 1152) x (1152 x 3584) -> gelu -> hb (bf16)
  k_gemm<0><<<dim3(HH / 128, (BB * TT) / 128), 256, 0, stream>>>(
      (const u16*)xb, (const u16*)w1t, b1, hb, BB * TT, HH, CC);
  // GEMM2: (8192 x 3584) x (3584 x 3584) -> + b2 -> d_out (fp32)
  k_gemm<1><<<dim3(HH / 128, (BB * TT) / 128), 256, 0, stream>>>(
      (const u16*)hb, (const u16*)w2t, b2, d_out, BB * TT, HH, HH);
}

// Round 4
// 1339.361 us; speedup vs baseline: 1.0732x; 1.0688x over previous
//
#include <hip/hip_runtime.h>
#include <hip/hip_bf16.h>
#include <stdint.h>

// Problem constants
#define BB 64
#define P0 729
#define CC 1152
#define HD 72        // CC / 16 heads
#define NHEAD 16
#define HH 3584
#define TT 128
#define NSTR 365     // max src count, stride for per-round index arrays
#define SCB 384      // padded row stride for partial-argmax buffers
#define MAXCB 6      // max column blocks (ceil(364/64))

typedef __hip_bfloat16 bf16;
typedef unsigned short u16;
typedef __attribute__((ext_vector_type(8))) short short8;
typedef __attribute__((ext_vector_type(4))) float floatx4;

__device__ inline u16 f2bf(float v) {
  bf16 h = __float2bfloat16(v);
  return *(u16*)&h;
}

__device__ inline void load_lds16(const void* g, void* l) {
  __builtin_amdgcn_global_load_lds(
      (const __attribute__((address_space(1))) uint32_t*)g,
      (__attribute__((address_space(3))) uint32_t*)l, 16, 0, 0);
}

// ---------------- init: fp64 head-mean of (x+pos), amap = identity ----------------
__global__ __launch_bounds__(128)
void k_init(const float* __restrict__ x, const float* __restrict__ pos,
            double* __restrict__ mo, int* __restrict__ amap) {
  __shared__ float xs[CC], ps[CC];
  int bp = blockIdx.x;           // b*729+p
  int p = bp % P0;
  int tid = threadIdx.x;         // 128
  const float4* xr = (const float4*)(x + (size_t)bp * CC);
  const float4* pr = (const float4*)(pos + (size_t)p * CC);
  for (int idx = tid; idx < CC / 4; idx += 128) {
    ((float4*)xs)[idx] = xr[idx];
    ((float4*)ps)[idx] = pr[idx];
  }
  __syncthreads();
  if (tid < HD) {
    double s = 0.0;
    #pragma unroll
    for (int h = 0; h < NHEAD; ++h) {
      int c = h * HD + tid;
      s += (double)xs[c] + (double)ps[c];
    }
    mo[(size_t)bp * HD + tid] = s * (1.0 / 16.0);
  }
  if (tid == 0) amap[bp] = p;
}

// ---------------- 1/||m|| per token (fp64) ----------------
__global__ void k_rnorm(const double* __restrict__ m, double* __restrict__ rn, int t) {
  int bi = blockIdx.x;           // b*t + i
  int lane = threadIdx.x;        // 64
  const double* row = m + (size_t)bi * HD;
  double v = 0.0;
  if (lane < HD) { double a = row[lane]; v = a * a; }
  if (lane < HD - 64) { double a = row[lane + 64]; v += a * a; }
  for (int off = 32; off; off >>= 1) v += __shfl_down(v, off, 64);
  if (lane == 0) {
    int b = bi / t, i = bi % t;
    rn[b * P0 + i] = 1.0 / sqrt(v);
  }
}

// ---------------- fp64 scores, 64x64 tile, 4x4 per thread ----------------
// Emits per-column-strip (max, first-argmax) partials; k_colred folds strips.
__global__ __launch_bounds__(256)
void k_score2(const double* __restrict__ m, const double* __restrict__ rn,
              double* __restrict__ pmax, int* __restrict__ pidx,
              int t, int s, int d) {
  __shared__ double sL[64][37];
  __shared__ double sD[64][37];
  int b = blockIdx.z;
  int i0 = blockIdx.x * 64, j0 = blockIdx.y * 64;
  int tid = threadIdx.x;
  int tx = tid & 15, ty = tid >> 4;
  double acc[4][4] = {};
  for (int kc = 0; kc < HD; kc += 36) {
    for (int idx = tid; idx < 64 * 36; idx += 256) {
      int row = idx / 36, k = idx - row * 36;
      int i = i0 + row;
      sL[row][k] = (i < s) ? m[((size_t)b * t + 2 * i) * HD + kc + k] : 0.0;
      int j = j0 + row;
      sD[row][k] = (j < d) ? m[((size_t)b * t + 2 * j + 1) * HD + kc + k] : 0.0;
    }
    __syncthreads();
    #pragma unroll 6
    for (int k = 0; k < 36; ++k) {
      double la[4], ld[4];
      #pragma unroll
      for (int a = 0; a < 4; ++a) la[a] = sL[ty + 16 * a][k];
      #pragma unroll
      for (int c = 0; c < 4; ++c) ld[c] = sD[tx + 16 * c][k];
      #pragma unroll
      for (int a = 0; a < 4; ++a)
        #pragma unroll
        for (int c = 0; c < 4; ++c)
          acc[a][c] += la[a] * ld[c];
    }
    __syncthreads();
  }
  #pragma unroll
  for (int a = 0; a < 4; ++a) {
    int i = i0 + ty + 16 * a;
    double rni = (i < s) ? rn[b * P0 + 2 * i] : 0.0;
    double best = -1e300; int bj = 0x7fffffff;
    #pragma unroll
    for (int c = 0; c < 4; ++c) {
      int j = j0 + tx + 16 * c;                       // ascending j per c
      double sc = (j < d) ? acc[a][c] * rni * rn[b * P0 + 2 * j + 1] : -1e300;
      if (sc > best) { best = sc; bj = j; }           // strict > keeps first max
    }
    for (int off = 8; off; off >>= 1) {
      double ov = __shfl_down(best, off, 16);
      int oj = __shfl_down(bj, off, 16);
      if (ov > best || (ov == best && oj < bj)) { best = ov; bj = oj; }
    }
    if (tx == 0 && i < s) {
      pmax[((size_t)b * MAXCB + blockIdx.y) * SCB + i] = best;
      pidx[((size_t)b * MAXCB + blockIdx.y) * SCB + i] = bj;
    }
  }
}

// ---------------- fold column-strip partials (ascending j, first-max) ----------
__global__ void k_colred(const double* __restrict__ pmax, const int* __restrict__ pidx,
                         double* __restrict__ nmax, int* __restrict__ nidx,
                         int s, int ncb) {
  int b = blockIdx.x, i = threadIdx.x;   // 512 >= s
  if (i >= s) return;
  double best = -1e300; int bj = 0x7fffffff;
  for (int cb = 0; cb < ncb; ++cb) {
    double v = pmax[((size_t)b * MAXCB + cb) * SCB + i];
    int j = pidx[((size_t)b * MAXCB + cb) * SCB + i];
    if (v > best) { best = v; bj = j; }  // cb ascending = j ascending
  }
  nmax[b * NSTR + i] = best; nidx[b * NSTR + i] = bj;
}

// ---------------- stable descending argsort (bitonic, idx tiebreak) ----------------
template <int SZ>
__global__ __launch_bounds__(512)
void k_sort(const double* __restrict__ nmax, int* __restrict__ eidx, int s) {
  __shared__ double v[SZ];
  __shared__ int ix[SZ];
  int b = blockIdx.x, tid = threadIdx.x;
  if (tid < s) { v[tid] = nmax[b * NSTR + tid]; ix[tid] = tid; }
  else { v[tid] = -1e308; ix[tid] = 1024 + tid; }
  __syncthreads();
  for (int k = 2; k <= SZ; k <<= 1)
    for (int j = k >> 1; j > 0; j >>= 1) {
      int l = tid ^ j;
      if (l > tid) {
        double va = v[tid], vb = v[l]; int ia = ix[tid], ib = ix[l];
        bool b_before_a = (vb > va) || (vb == va && ib < ia);
        bool a_before_b = (va > vb) || (va == vb && ia < ib);
        bool dir = ((tid & k) == 0);
        bool sw = dir ? b_before_a : a_before_b;
        if (sw) { v[tid] = vb; v[l] = va; ix[tid] = ib; ix[l] = ia; }
      }
      __syncthreads();
    }
  if (tid < s) eidx[b * NSTR + tid] = ix[tid];
}

// ---------------- compose per-round old->new map into amap (orig token -> slot) ----
__global__ __launch_bounds__(512)
void k_mapround(const int* __restrict__ eidx, const int* __restrict__ nidx,
                int* __restrict__ amap, int t, int s, int r, int unm) {
  __shared__ int pos_of[NSTR];
  __shared__ int rmap[P0];
  int b = blockIdx.x, tid = threadIdx.x;
  for (int q = tid; q < s; q += 512) pos_of[eidx[b * NSTR + q]] = q;
  __syncthreads();
  for (int j = tid; j < t; j += 512) {
    int nm;
    if (j & 1) {
      nm = unm + (j >> 1);                      // odd token = dst jd -> unm + jd
    } else {
      int i = j >> 1;                           // even token = src i
      int q = pos_of[i];
      nm = (q >= r) ? (q - r)                   // unmerged: position in unm block
                    : (unm + nidx[b * NSTR + i]); // merged into its dst
    }
    rmap[j] = nm;
  }
  __syncthreads();
  for (int p = tid; p < P0; p += 512) {
    int cur = amap[b * P0 + p];
    amap[b * P0 + p] = rmap[cur];
  }
}

// ---------------- fp64 metric merge: gather then scatter-add ----------------
__global__ void k_gather_d(const double* __restrict__ mo, double* __restrict__ mn,
                           const int* __restrict__ eidx,
                           int t, int r, int unm, int tnew) {
  size_t idx = (size_t)blockIdx.x * 256 + threadIdx.x;
  size_t total = (size_t)BB * tnew * HD;
  if (idx >= total) return;
  int k = idx % HD;
  int o = (idx / HD) % tnew;
  int b = idx / ((size_t)HD * tnew);
  int tok = (o < unm) ? 2 * eidx[b * NSTR + r + o] : 2 * (o - unm) + 1;
  mn[idx] = mo[((size_t)b * t + tok) * HD + k];
}

__global__ void k_scatter_d(const double* __restrict__ mo, double* __restrict__ mn,
                            const int* __restrict__ eidx, const int* __restrict__ nidx,
                            int t, int r, int unm, int tnew) {
  size_t idx = (size_t)blockIdx.x * 256 + threadIdx.x;
  size_t total = (size_t)BB * r * HD;
  if (idx >= total) return;
  int k = idx % HD;
  int q = (idx / HD) % r;
  int b = idx / ((size_t)HD * r);
  int si = eidx[b * NSTR + q];
  int di = nidx[b * NSTR + si];
  atomicAdd(&mn[((size_t)b * tnew + unm + di) * HD + k],
            mo[((size_t)b * t + 2 * si) * HD + k]);
}

// ---------------- CSR build: counts (=sizes), offsets, member lists ----------------
__global__ __launch_bounds__(256)
void k_buildcsr(const int* __restrict__ amap, int* __restrict__ sizes,
                int* __restrict__ offs, int* __restrict__ list) {
  __shared__ int cnt[TT], off_s[TT], cur[TT];
  int b = blockIdx.x, tid = threadIdx.x;
  if (tid < TT) { cnt[tid] = 0; cur[tid] = 0; }
  __syncthreads();
  for (int p = tid; p < P0; p += 256) atomicAdd(&cnt[amap[b * P0 + p]], 1);
  __syncthreads();
  if (tid == 0) {
    int acc = 0;
    for (int o = 0; o < TT; ++o) { off_s[o] = acc; acc += cnt[o]; }
  }
  __syncthreads();
  if (tid < TT) { sizes[b * TT + tid] = cnt[tid]; offs[b * TT + tid] = off_s[tid]; }
  for (int p = tid; p < P0; p += 256) {
    int o = amap[b * P0 + p];
    int pos = atomicAdd(&cur[o], 1);
    list[b * P0 + off_s[o] + pos] = p;
  }
}

// ---------------- final assembly: sum assigned (x+pos) rows, /size, -> bf16 --------
__global__ __launch_bounds__(256)
void k_assemble(const float* __restrict__ x, const float* __restrict__ pos,
                const int* __restrict__ sizes, const int* __restrict__ offs,
                const int* __restrict__ list, bf16* __restrict__ xb) {
  int o = blockIdx.x, b = blockIdx.y, tid = threadIdx.x;
  int n = sizes[b * TT + o];
  int off = offs[b * TT + o];
  const int C4 = CC / 4;  // 288 float4 per row; thread covers tid and tid+256 (if <32)
  float4 a0 = {0.f, 0.f, 0.f, 0.f}, a1 = {0.f, 0.f, 0.f, 0.f};
  for (int i = 0; i < n; ++i) {
    int p = list[b * P0 + off + i];
    const float4* xr = (const float4*)(x + ((size_t)b * P0 + p) * CC);
    const float4* pr = (const float4*)(pos + (size_t)p * CC);
    float4 v = xr[tid], w = pr[tid];
    a0.x += v.x + w.x; a0.y += v.y + w.y; a0.z += v.z + w.z; a0.w += v.w + w.w;
    if (tid < C4 - 256) {
      float4 v1 = xr[tid + 256], w1 = pr[tid + 256];
      a1.x += v1.x + w1.x; a1.y += v1.y + w1.y; a1.z += v1.z + w1.z; a1.w += v1.w + w1.w;
    }
  }
  float inv = 1.0f / (float)n;
  bf16* orow = xb + ((size_t)b * TT + o) * CC;
  ushort4 pk;
  pk.x = f2bf(a0.x * inv);
  pk.y = f2bf(a0.y * inv);
  pk.z = f2bf(a0.z * inv);
  pk.w = f2bf(a0.w * inv);
  ((ushort4*)orow)[tid] = pk;
  if (tid < C4 - 256) {
    ushort4 pk1;
    pk1.x = f2bf(a1.x * inv);
    pk1.y = f2bf(a1.y * inv);
    pk1.z = f2bf(a1.z * inv);
    pk1.w = f2bf(a1.w * inv);
    ((ushort4*)orow)[tid + 256] = pk1;
  }
}

// ---------------- transpose + cast weights: (K,N) fp32 -> (N,K) bf16 ----------------
__global__ void k_transpose(const float* __restrict__ w, bf16* __restrict__ wt,
                            int K, int N) {
  __shared__ float tile[32][33];
  int n0 = blockIdx.x * 32, k0 = blockIdx.y * 32;
  int tx = threadIdx.x, ty = threadIdx.y;   // 32 x 8
  #pragma unroll
  for (int yy = 0; yy < 32; yy += 8)
    tile[ty + yy][tx] = w[(size_t)(k0 + ty + yy) * N + n0 + tx];
  __syncthreads();
  #pragma unroll
  for (int yy = 0; yy < 32; yy += 8)
    wt[(size_t)(n0 + ty + yy) * K + k0 + tx] = __float2bfloat16(tile[tx][ty + yy]);
}

// ---------------- bf16 MFMA GEMM, A (M,K) row-major, Bt (N,K) row-major ----------------
// EPI 0: out = bf16(gelu_exact(acc + bias))   EPI 1: out = fp32(acc + bias)
template <int EPI>
__global__ __launch_bounds__(256)
void k_gemm(const u16* __restrict__ A, const u16* __restrict__ Bt,
            const float* __restrict__ bias, void* __restrict__ Cout,
            int M, int N, int K) {
  __shared__ u16 sA[128 * 32];
  __shared__ u16 sB[128 * 32];
  int tid = threadIdx.x;
  int m0 = blockIdx.y * 128, n0 = blockIdx.x * 128;
  int wave = tid >> 6, lane = tid & 63;
  int wm = (wave & 1) * 64, wn = (wave >> 1) * 64;
  int quad = lane >> 4, lrow = lane & 15;
  floatx4 acc[4][4] = {};
  const u16* gA = A + (size_t)(m0 + tid / 4) * K + (tid % 4) * 8;
  const u16* gB = Bt + (size_t)(n0 + tid / 4) * K + (tid % 4) * 8;
  for (int k0 = 0; k0 < K; k0 += 32) {
    load_lds16(gA + k0, &sA[tid * 8]);
    load_lds16(gA + (size_t)64 * K + k0, &sA[2048 + tid * 8]);
    load_lds16(gB + k0, &sB[tid * 8]);
    load_lds16(gB + (size_t)64 * K + k0, &sB[2048 + tid * 8]);
    __syncthreads();
    short8 af[4], bfr[4];
    #pragma unroll
    for (int mt = 0; mt < 4; ++mt)
      af[mt] = *(const short8*)&sA[(wm + mt * 16 + lrow) * 32 + quad * 8];
    #pragma unroll
    for (int nt = 0; nt < 4; ++nt)
      bfr[nt] = *(const short8*)&sB[(wn + nt * 16 + lrow) * 32 + quad * 8];
    #pragma unroll
    for (int mt = 0; mt < 4; ++mt)
      #pragma unroll
      for (int nt = 0; nt < 4; ++nt)
        acc[mt][nt] = __builtin_amdgcn_mfma_f32_16x16x32_bf16(af[mt], bfr[nt], acc[mt][nt], 0, 0, 0);
    __syncthreads();
  }
  #pragma unroll
  for (int mt = 0; mt < 4; ++mt)
    #pragma unroll
    for (int nt = 0; nt < 4; ++nt)
      #pragma unroll
      for (int rg = 0; rg < 4; ++rg) {
        int row = m0 + wm + mt * 16 + quad * 4 + rg;
        int col = n0 + wn + nt * 16 + lrow;
        float v = acc[mt][nt][rg] + bias[col];
        if (EPI == 0) {
          float g = 0.5f * v * (1.0f + erff(v * 0.70710678118654752f));
          ((bf16*)Cout)[(size_t)row * N + col] = __float2bfloat16(g);
        } else {
          ((float*)Cout)[(size_t)row * N + col] = v;
        }
      }
}

extern "C" void kernel_launch(void* const* d_in, const int* in_sizes, int n_in,
                              void* d_out, int out_size, void* d_ws, size_t ws_size,
                              hipStream_t stream) {
  const float* x   = (const float*)d_in[0];
  const float* pos = (const float*)d_in[1];
  const float* w1  = (const float*)d_in[2];
  const float* b1  = (const float*)d_in[3];
  const float* w2  = (const float*)d_in[4];
  const float* b2  = (const float*)d_in[5];

  uint8_t* wsp = (uint8_t*)d_ws;
  size_t off = 0;
  auto alloc = [&](size_t bytes) -> void* {
    void* p = wsp + off;
    off += (bytes + 255) & ~(size_t)255;
    return p;
  };
  double* m_a  = (double*)alloc((size_t)BB * P0 * HD * 8);      // 26.9 MB
  double* m_b  = (double*)alloc((size_t)BB * NSTR * HD * 8);    // 13.5 MB
  double* rn   = (double*)alloc((size_t)BB * P0 * 8);
  double* nmax = (double*)alloc((size_t)BB * NSTR * 8);
  int*    nidx = (int*)alloc((size_t)BB * NSTR * 4);
  int*    eidx = (int*)alloc((size_t)BB * NSTR * 4);
  double* pmax = (double*)alloc((size_t)BB * MAXCB * SCB * 8);  // 1.18 MB
  int*    pidx = (int*)alloc((size_t)BB * MAXCB * SCB * 4);
  int*    amap = (int*)alloc((size_t)BB * P0 * 4);
  int*    szs  = (int*)alloc((size_t)BB * TT * 4);
  int*    offs = (int*)alloc((size_t)BB * TT * 4);
  int*    list = (int*)alloc((size_t)BB * P0 * 4);
  bf16*   xb   = (bf16*)alloc((size_t)BB * TT * CC * 2);        // 18.9 MB
  bf16*   w1t  = (bf16*)alloc((size_t)HH * CC * 2);             // 8.3 MB
  bf16*   w2t  = (bf16*)alloc((size_t)HH * HH * 2);             // 25.7 MB
  bf16*   hb   = (bf16*)alloc((size_t)BB * TT * HH * 2);        // 58.7 MB

  k_init<<<BB * P0, 128, 0, stream>>>(x, pos, m_a, amap);
  dim3 tb(32, 8);
  k_transpose<<<dim3(HH / 32, CC / 32), tb, 0, stream>>>(w1, w1t, CC, HH);
  k_transpose<<<dim3(HH / 32, HH / 32), tb, 0, stream>>>(w2, w2t, HH, HH);

  struct Rnd { int t, s, d, r, unm, tnew; };
  const Rnd R[3] = {{729, 365, 364, 364, 1, 365},
                    {365, 183, 182, 182, 1, 183},
                    {183,  92,  91,  55, 37, 128}};
  double* msrc[3] = {m_a, m_b, m_a};
  double* mdst[3] = {m_b, m_a, m_b};

  for (int rr = 0; rr < 3; ++rr) {
    Rnd q = R[rr];
    k_rnorm<<<BB * q.t, 64, 0, stream>>>(msrc[rr], rn, q.t);
    int rt = (q.s + 63) / 64, ct = (q.d + 63) / 64;
    dim3 sg(rt, ct, BB);
    k_score2<<<sg, 256, 0, stream>>>(msrc[rr], rn, pmax, pidx, q.t, q.s, q.d);
    k_colred<<<BB, 512, 0, stream>>>(pmax, pidx, nmax, nidx, q.s, ct);
    if (rr == 0)      k_sort<512><<<BB, 512, 0, stream>>>(nmax, eidx, q.s);
    else if (rr == 1) k_sort<256><<<BB, 256, 0, stream>>>(nmax, eidx, q.s);
    else              k_sort<128><<<BB, 128, 0, stream>>>(nmax, eidx, q.s);
    k_mapround<<<BB, 512, 0, stream>>>(eidx, nidx, amap, q.t, q.s, q.r, q.unm);
    if (rr < 2) {  // metric for next round only
      size_t tg = (size_t)BB * q.tnew * HD;
      k_gather_d<<<(tg + 255) / 256, 256, 0, stream>>>(msrc[rr], mdst[rr], eidx, q.t, q.r, q.unm, q.tnew);
      size_t ts = (size_t)BB * q.r * HD;
      k_scatter_d<<<(ts + 255) / 256, 256, 0, stream>>>(msrc[rr], mdst[rr], eidx, nidx, q.t, q.r, q.unm, q.tnew);
    }
  }

  k_buildcsr<<<BB, 256, 0, stream>>>(amap, szs, offs, list);
  k_assemble<<<dim3(TT, BB), 256, 0, stream>>>(x, pos, szs, offs, list, xb);

  // GEMM1: (8192 x 1152) x (1152 x 3584) -> gelu -> hb (bf16)
  k_gemm<0><<<dim3(HH / 128, (BB * TT) / 128), 256, 0, stream>>>(
      (const u16*)xb, (const u16*)w1t, b1, hb, BB * TT, HH, CC);
  // GEMM2: (8192 x 3584) x (3584 x 3584) -> + b2 -> d_out (fp32)
  k_gemm<1><<<dim3(HH / 128, (BB * TT) / 128), 256, 0, stream>>>(
      (const u16*)hb, (const u16*)w2t, b2, d_out, BB * TT, HH, HH);
}